// Round 7
// baseline (5384.728 us; speedup 1.0000x reference)
//
#include <hip/hip_runtime.h>
#include <hip/hip_bf16.h>
#include <stdint.h>

// BidLSTM: B=64, T=1000, C=320, U=320.
// Phase 1: Zx[dir][slice][t][b][64] = bf16(X@W + b), slice-local col = g*16 + (u&15).
// Phase 2: persistent kernel, 40 WGs (20/dir, 16 units each), U^T in registers as the
//          MFMA ROW operand so D[unit][batch]: each lane's acc[g] holds all 4 gates for
//          its own (batch, 4 units) — NO LDS, NO barriers in the loop. Data-as-signal
//          sentinel ring over the round-5-proven agent-atomic transport; reset ordering
//          via one vmcnt(0) immediately before each h-store.

#define Bx 64
#define Tx 1000
#define Cx 320
#define NSLICE 20   // WGs per direction
#define UPW 16      // units per WG
#define SENT 0xFFFFFFFFFFFFFFFFull

typedef __attribute__((ext_vector_type(8))) short short8;
typedef __attribute__((ext_vector_type(4))) short short4v;
typedef __attribute__((ext_vector_type(4))) float f32x4;

__device__ inline unsigned short f2bf(float f) {
  unsigned x = __builtin_bit_cast(unsigned, f);
  x += 0x7fffu + ((x >> 16) & 1u);
  return (unsigned short)(x >> 16);
}
__device__ inline float bf2f(unsigned short u) {
  unsigned x = ((unsigned)u) << 16;
  return __builtin_bit_cast(float, x);
}

// ---- ws layout (bytes) ----
// Xb region [0, 40.96 MB) is dead after k_gemm; mask2/hring overlay it.
#define OFF_MB   0ull                 // mask2 [1000] u64 = 8,000
#define OFF_HB   16384ull             // hring [4slot][2dir][64][320] bf16 = 327,680
#define OFF_XB   0ull                 // Xb [64000][320] bf16 (pre-GEMM only)
#define OFF_WT   40960000ull          // Wt [2][1280][320] bf16 = 1,638,400
#define OFF_BP   42598400ull          // bias [2][1280] f32 = 10,240
#define OFF_ZX   42608640ull          // Zx [2][20][1000][4096] bf16 = 327,680,000
// total = 370,288,640 (same footprint as rounds 1-5 — proven to fit)

// Convert X [b][t][c] f32 -> Xb [(t*64+b)][c] bf16
__global__ __launch_bounds__(256) void k_prep_x(const float* __restrict__ X,
                                                unsigned short* __restrict__ Xb) {
  int i4 = blockIdx.x * 256 + threadIdx.x;
  if (i4 >= Bx * Tx * Cx / 4) return;
  int idx = i4 * 4;
  int b = idx / (Tx * Cx);
  int rem = idx - b * (Tx * Cx);
  int t = rem / Cx;
  int c = rem - t * Cx;
  float4 v = *(const float4*)(X + idx);
  short4v o;
  o[0] = (short)f2bf(v.x); o[1] = (short)f2bf(v.y);
  o[2] = (short)f2bf(v.z); o[3] = (short)f2bf(v.w);
  *(short4v*)(Xb + (size_t)(t * Bx + b) * Cx + c) = o;
}

// Wt[dir][n][k] = bf16(W[dir][k][n]) (no permutation); biasp[dir][n] = b[n]
__global__ __launch_bounds__(256) void k_prep_w(const float* __restrict__ Wf,
                                                const float* __restrict__ Wb,
                                                const float* __restrict__ bfv,
                                                const float* __restrict__ bbv,
                                                unsigned short* __restrict__ Wt,
                                                float* __restrict__ biasp) {
  int gid = blockIdx.x * 256 + threadIdx.x;
  if (gid < 2 * 1280 * 320) {
    int dir = gid / (1280 * 320);
    int rem = gid - dir * 1280 * 320;
    int n = rem / 320;
    int k = rem - n * 320;
    const float* W = dir ? Wb : Wf;
    Wt[gid] = f2bf(W[k * 1280 + n]);
  }
  if (gid < 2 * 1280) {
    int dir = gid / 1280, n = gid - dir * 1280;
    const float* bsrc = dir ? bbv : bfv;
    biasp[gid] = bsrc[n];
  }
}

// mask2[t] = bitmask over batches (bit b = mask[b][t]); detects byte vs int32 mask.
__global__ __launch_bounds__(256) void k_prep_mask(const void* __restrict__ maskp,
                                                   unsigned long long* __restrict__ mask2) {
  int t = blockIdx.x * 256 + threadIdx.x;
  if (t >= Tx) return;
  const unsigned* mw = (const unsigned*)maskp;
  const bool mbyte = (mw[0] == 0x01010101u);
  unsigned long long wv = 0ull;
  if (mbyte) {
    const unsigned char* m8 = (const unsigned char*)maskp;
#pragma unroll 8
    for (int b = 0; b < Bx; b++)
      wv |= (unsigned long long)(m8[b * Tx + t] & 1) << b;
  } else {
    const int* m32 = (const int*)maskp;
#pragma unroll 8
    for (int b = 0; b < Bx; b++)
      wv |= (unsigned long long)(m32[b * Tx + t] & 1) << b;
  }
  mask2[t] = wv;
}

// C = A @ Bt^T + bias; Zx element = [dir,sl][t][b*64 + (g*16 + (u&15))].
__global__ __launch_bounds__(256) void k_gemm(const unsigned short* __restrict__ A,
                                              const unsigned short* __restrict__ Bt,
                                              const float* __restrict__ biasp,
                                              unsigned short* __restrict__ Czx) {
  int bid = blockIdx.x;
  int dir = bid / 5000;
  int r = bid - dir * 5000;
  int tm = r / 10, tn = r - (r / 10) * 10;
  long m0 = (long)tm * 128;
  int n0 = tn * 128;
  const unsigned short* Bd = Bt + (size_t)dir * 1280 * 320;
  const float* bias = biasp + dir * 1280;

  __shared__ __align__(16) unsigned short As[128 * 64];
  __shared__ __align__(16) unsigned short Bs[128 * 64];

  int tid = threadIdx.x;
  int wave = tid >> 6, lane = tid & 63;
  int l15 = lane & 15, l4 = lane >> 4;

  f32x4 acc[2][8];
#pragma unroll
  for (int i = 0; i < 2; i++)
#pragma unroll
    for (int j = 0; j < 8; j++) acc[i][j] = (f32x4){0.f, 0.f, 0.f, 0.f};

  for (int k0 = 0; k0 < 320; k0 += 64) {
    __syncthreads();
#pragma unroll
    for (int it = 0; it < 4; it++) {
      int idx = it * 256 + tid;
      int rr = idx >> 3, cc = idx & 7;
      const unsigned short* ga = A + (size_t)(m0 + rr) * 320 + k0 + cc * 8;
      unsigned short* la = As + (size_t)(it * 256 + wave * 64) * 8;
      __builtin_amdgcn_global_load_lds(
          (const __attribute__((address_space(1))) void*)ga,
          (__attribute__((address_space(3))) void*)la, 16, 0, 0);
      const unsigned short* gb = Bd + (size_t)(n0 + rr) * 320 + k0 + cc * 8;
      unsigned short* lb = Bs + (size_t)(it * 256 + wave * 64) * 8;
      __builtin_amdgcn_global_load_lds(
          (const __attribute__((address_space(1))) void*)gb,
          (__attribute__((address_space(3))) void*)lb, 16, 0, 0);
    }
    __syncthreads();
#pragma unroll
    for (int kk = 0; kk < 2; kk++) {
      short8 af[2], bf8[8];
#pragma unroll
      for (int mf = 0; mf < 2; mf++)
        af[mf] = *(const short8*)(As + (wave * 32 + mf * 16 + l15) * 64 + kk * 32 + l4 * 8);
#pragma unroll
      for (int nf = 0; nf < 8; nf++)
        bf8[nf] = *(const short8*)(Bs + (nf * 16 + l15) * 64 + kk * 32 + l4 * 8);
#pragma unroll
      for (int mf = 0; mf < 2; mf++)
#pragma unroll
        for (int nf = 0; nf < 8; nf++)
          acc[mf][nf] = __builtin_amdgcn_mfma_f32_16x16x32_bf16(af[mf], bf8[nf], acc[mf][nf], 0, 0, 0);
    }
  }
  // epilogue: original col -> (g, u); store at [t][b*64 + g*16 + (u&15)]
#pragma unroll
  for (int mf = 0; mf < 2; mf++) {
#pragma unroll
    for (int nf = 0; nf < 8; nf++) {
      int col = n0 + nf * 16 + l15;
      float bv = bias[col];
      int g = col / 320;
      int u = col - g * 320;
      int sl = u >> 4;
      int cp = g * 16 + (u & 15);
      size_t sbase = ((size_t)(dir * NSLICE + sl)) * Tx * 4096;
#pragma unroll
      for (int i = 0; i < 4; i++) {
        long m = m0 + wave * 32 + mf * 16 + l4 * 4 + i;
        long t = m >> 6;
        int b = (int)(m & 63);
        Czx[sbase + (size_t)t * 4096 + b * 64 + cp] = f2bf(acc[mf][nf][i] + bv);
      }
    }
  }
}

// Persistent recurrent kernel. 40 WGs x 256 threads; waves fully independent
// (wave w = batch plane 16w..16w+15). No barriers in the step loop.
__global__ __launch_bounds__(256, 1) void k_lstm(const unsigned short* __restrict__ Zx,
                                                 const float* __restrict__ Uf,
                                                 const float* __restrict__ Ub,
                                                 const unsigned long long* __restrict__ mask2,
                                                 unsigned short* __restrict__ hring,
                                                 float* __restrict__ out) {
  const int w = blockIdx.x;
  const int dir = w / NSLICE;
  const int slice = w - dir * NSLICE;
  const int u0 = slice * UPW;
  const int tid = threadIdx.x;
  const int wave = tid >> 6, lane = tid & 63;
  const int l15 = lane & 15, q4 = lane >> 4;

  // U^T as the MFMA ROW operand: bfrag[g][kt] lane holds A[row=l15][k=kt*32+q4*8+j]
  //   = U[k][g*320 + u0 + l15]   (D rows = units-in-slice, D cols = batches)
  const float* U = dir ? Ub : Uf;
  short8 bfrag[4][10];
#pragma unroll
  for (int g = 0; g < 4; g++) {
    int colU = g * 320 + u0 + l15;
#pragma unroll
    for (int kt = 0; kt < 10; kt++) {
      short8 v;
#pragma unroll
      for (int j = 0; j < 8; j++)
        v[j] = (short)f2bf(U[(size_t)(kt * 32 + q4 * 8 + j) * 1280 + colU]);
      bfrag[g][kt] = v;
    }
  }

  const int b = 16 * wave + l15;        // this lane's batch (C col = l15)
  // lane owns (batch b, units u0+4*q4+r), r=0..3 (C rows m = 4*q4+r)
  float cst0 = 0.f, cst1 = 0.f, cst2 = 0.f, cst3 = 0.f;
  float hst0 = 0.f, hst1 = 0.f, hst2 = 0.f, hst3 = 0.f;

  const unsigned short* zbase = Zx + ((size_t)(dir * NSLICE + slice)) * Tx * 4096;
#define HR(SL) (hring + ((size_t)((SL) * 2 + dir)) * Bx * 320)

  // prefetch step 0: Zx (4 u64: gate g block) + mask
  int t = dir ? (Tx - 1) : 0;
  unsigned long long zx0 = *(const unsigned long long*)(zbase + (size_t)t * 4096 + b * 64 + 0 * 16 + 4 * q4);
  unsigned long long zx1 = *(const unsigned long long*)(zbase + (size_t)t * 4096 + b * 64 + 1 * 16 + 4 * q4);
  unsigned long long zx2 = *(const unsigned long long*)(zbase + (size_t)t * 4096 + b * 64 + 2 * 16 + 4 * q4);
  unsigned long long zx3 = *(const unsigned long long*)(zbase + (size_t)t * 4096 + b * 64 + 3 * 16 + 4 * q4);
  unsigned long long mwrd = mask2[t];

  unsigned long long q[20];            // in-flight poll values (row b, all 320 k)
  const unsigned short* pollb = nullptr;

  for (int s = 0;; ++s) {
    t = dir ? (Tx - 1 - s) : s;
    f32x4 acc0 = {0.f, 0.f, 0.f, 0.f}, acc1 = {0.f, 0.f, 0.f, 0.f};
    f32x4 acc2 = {0.f, 0.f, 0.f, 0.f}, acc3 = {0.f, 0.f, 0.f, 0.f};
    if (s > 0) {
      // complete the poll issued at the end of step s-1: all 20 words != SENT
      unsigned spin = 0;
      for (;;) {
        bool any = false;
#pragma unroll
        for (int i = 0; i < 20; i++) any |= (q[i] == SENT);
        if (!any) break;
        if (++spin > 65536u) break;  // broken protocol -> clean validation fail
#pragma unroll
        for (int i = 0; i < 20; i++)
          if (q[i] == SENT)
            q[i] = __hip_atomic_load(
                (const unsigned long long*)(pollb + (i >> 1) * 32 + q4 * 8 + (i & 1) * 4),
                __ATOMIC_RELAXED, __HIP_MEMORY_SCOPE_AGENT);
      }
      // B-frag (h) from polled words; D[m][b] accumulated per gate tile
      short8 afr[10];
#pragma unroll
      for (int kt = 0; kt < 10; kt++) {
        union { unsigned long long qq[2]; short8 v; } u;
        u.qq[0] = q[2 * kt];
        u.qq[1] = q[2 * kt + 1];
        afr[kt] = u.v;
      }
#pragma unroll
      for (int k2 = 0; k2 < 5; k2++) {
        acc0 = __builtin_amdgcn_mfma_f32_16x16x32_bf16(bfrag[0][2 * k2], afr[2 * k2], acc0, 0, 0, 0);
        acc1 = __builtin_amdgcn_mfma_f32_16x16x32_bf16(bfrag[1][2 * k2], afr[2 * k2], acc1, 0, 0, 0);
        acc2 = __builtin_amdgcn_mfma_f32_16x16x32_bf16(bfrag[2][2 * k2], afr[2 * k2], acc2, 0, 0, 0);
        acc3 = __builtin_amdgcn_mfma_f32_16x16x32_bf16(bfrag[3][2 * k2], afr[2 * k2], acc3, 0, 0, 0);
        acc0 = __builtin_amdgcn_mfma_f32_16x16x32_bf16(bfrag[0][2 * k2 + 1], afr[2 * k2 + 1], acc0, 0, 0, 0);
        acc1 = __builtin_amdgcn_mfma_f32_16x16x32_bf16(bfrag[1][2 * k2 + 1], afr[2 * k2 + 1], acc1, 0, 0, 0);
        acc2 = __builtin_amdgcn_mfma_f32_16x16x32_bf16(bfrag[2][2 * k2 + 1], afr[2 * k2 + 1], acc2, 0, 0, 0);
        acc3 = __builtin_amdgcn_mfma_f32_16x16x32_bf16(bfrag[3][2 * k2 + 1], afr[2 * k2 + 1], acc3, 0, 0, 0);
      }
    }

    // gates: acc{g}[r] + Zx(g,r) for (batch b, unit u0+4*q4+r) — all in-lane
    int mv = (int)((mwrd >> b) & 1ull);
#define GATES(R, CC, HH)                                               \
    {                                                                  \
      float zi = acc0[R] + bf2f((unsigned short)(zx0 >> (16 * R)));    \
      float zf = acc1[R] + bf2f((unsigned short)(zx1 >> (16 * R)));    \
      float zg = acc2[R] + bf2f((unsigned short)(zx2 >> (16 * R)));    \
      float zo = acc3[R] + bf2f((unsigned short)(zx3 >> (16 * R)));    \
      float ig = 1.f / (1.f + __expf(-zi));                            \
      float fg = 1.f / (1.f + __expf(-zf));                            \
      float gg = 2.f / (1.f + __expf(-2.f * zg)) - 1.f;                \
      float og = 1.f / (1.f + __expf(-zo));                            \
      float cn = fg * (CC) + ig * gg;                                  \
      float hn = og * (2.f / (1.f + __expf(-2.f * cn)) - 1.f);         \
      if (mv) { (CC) = cn; (HH) = hn; }                                \
    }
    GATES(0, cst0, hst0)
    GATES(1, cst1, hst1)
    GATES(2, cst2, hst2)
    GATES(3, cst3, hst3)
#undef GATES

    // drain everything issued in prior steps (resets, out, Zx prefetch — all old)
    // => reset(slot X, step s-1) is globally ordered before h-store(slot X, s+1..)
    asm volatile("s_waitcnt vmcnt(0)" ::: "memory");

    if (s < Tx - 1) {
      // h publish: the data IS the signal (write-once into slot s&3)
      unsigned long long hv =
          (unsigned long long)f2bf(hst0) | ((unsigned long long)f2bf(hst1) << 16) |
          ((unsigned long long)f2bf(hst2) << 32) | ((unsigned long long)f2bf(hst3) << 48);
      __hip_atomic_store((unsigned long long*)(HR(s & 3) + b * 320 + u0 + 4 * q4),
                         hv, __ATOMIC_RELAXED, __HIP_MEMORY_SCOPE_AGENT);
    }

    // out: one float4 per lane (16B, contiguous units) — off the critical path
    float4 ov = make_float4(hst0, hst1, hst2, hst3);
    *(float4*)(out + ((size_t)b * Tx + t) * 640 + dir * 320 + u0 + 4 * q4) = ov;
    if (s == Tx - 1) {
      *(float4*)(out + 40960000ull + (size_t)b * 640 + dir * 320 + u0 + 4 * q4) = ov;
      break;  // uniform
    }

    // reset slot (s+2)&3 (holds h^{s-2}; all its consumers provably done)
    __hip_atomic_store((unsigned long long*)(HR((s + 2) & 3) + b * 320 + u0 + 4 * q4),
                       SENT, __ATOMIC_RELAXED, __HIP_MEMORY_SCOPE_AGENT);

    // prefetch next step's Zx + mask (issued AFTER the vmcnt(0)/h-store)
    int tn = dir ? (Tx - 2 - s) : (s + 1);
    zx0 = *(const unsigned long long*)(zbase + (size_t)tn * 4096 + b * 64 + 0 * 16 + 4 * q4);
    zx1 = *(const unsigned long long*)(zbase + (size_t)tn * 4096 + b * 64 + 1 * 16 + 4 * q4);
    zx2 = *(const unsigned long long*)(zbase + (size_t)tn * 4096 + b * 64 + 2 * 16 + 4 * q4);
    zx3 = *(const unsigned long long*)(zbase + (size_t)tn * 4096 + b * 64 + 3 * 16 + 4 * q4);
    mwrd = mask2[tn];

    // issue next poll round (slot s&3, row b) — hides one fabric RT
    pollb = HR(s & 3) + b * 320;
#pragma unroll
    for (int i = 0; i < 20; i++)
      q[i] = __hip_atomic_load(
          (const unsigned long long*)(pollb + (i >> 1) * 32 + q4 * 8 + (i & 1) * 4),
          __ATOMIC_RELAXED, __HIP_MEMORY_SCOPE_AGENT);
  }
#undef HR
}

extern "C" void kernel_launch(void* const* d_in, const int* in_sizes, int n_in,
                              void* d_out, int out_size, void* d_ws, size_t ws_size,
                              hipStream_t stream) {
  const float* X = (const float*)d_in[0];
  const void* Mk = d_in[1];
  const float* Wf = (const float*)d_in[2];
  const float* Uf = (const float*)d_in[3];
  const float* bfv = (const float*)d_in[4];
  const float* Wb = (const float*)d_in[5];
  const float* Ub = (const float*)d_in[6];
  const float* bbv = (const float*)d_in[7];

  char* ws = (char*)d_ws;
  unsigned short* Xb = (unsigned short*)(ws + OFF_XB);
  unsigned short* Wt = (unsigned short*)(ws + OFF_WT);
  float* bp = (float*)(ws + OFF_BP);
  unsigned short* Zx = (unsigned short*)(ws + OFF_ZX);
  unsigned long long* mask2 = (unsigned long long*)(ws + OFF_MB);
  unsigned short* hring = (unsigned short*)(ws + OFF_HB);

  k_prep_x<<<dim3(20000), dim3(256), 0, stream>>>(X, Xb);
  k_prep_w<<<dim3(3200), dim3(256), 0, stream>>>(Wf, Wb, bfv, bbv, Wt, bp);
  k_gemm<<<dim3(10000), dim3(256), 0, stream>>>(Xb, Wt, bp, Zx);
  // mask2/hring overlay the (now dead) Xb region — initialize after k_gemm
  hipMemsetAsync(ws + OFF_HB, 0xFF, 327680, stream);  // hring = all-sentinel
  k_prep_mask<<<dim3(4), dim3(256), 0, stream>>>(Mk, mask2);
  k_lstm<<<dim3(2 * NSLICE), dim3(256), 0, stream>>>(Zx, Uf, Ub, mask2, hring,
                                                     (float*)d_out);
}